// Round 10
// baseline (222.900 us; speedup 1.0000x reference)
//
#include <hip/hip_runtime.h>
#include <hip/hip_bf16.h>

#define BLOCK   512     // 8 waves; wave w owns channels w*16..w*16+15, all 4 gates
#define NSAMP   16
#define HDIM    128
#define DDIM    16
#define NOBJ    6
#define NSLOT   16

typedef __attribute__((ext_vector_type(8))) short bf16x8;
typedef __attribute__((ext_vector_type(4))) float f32x4;

constexpr int pc6(int m)  { int c = 0; for (int i = 0; i < 6; ++i) c += (m >> i) & 1; return c; }
constexpr int msb6(int m) { int b = -1; for (int i = 0; i < 6; ++i) if (m & (1 << i)) b = i; return b; }

// Compile-time BFS plan with 16-slot allocator (verified R6-R9).
struct NodeRec { int jo, ps, sl; };
struct Plan { int cnt[7]; int n1[7]; NodeRec nd[7][20]; };
constexpr Plan make_plan() {
    Plan P{};
    int slotOf[64] = {};
    bool busy[NSLOT] = {};
    for (int d = 1; d <= 6; ++d) {
        int n = 0;
        for (int M = 1; M < 64; ++M) {            // phase 1a: leaf children
            if (pc6(M) != d || msb6(M) != 5) continue;
            P.nd[d][n].jo = 5;
            P.nd[d][n].ps = (d == 1) ? -1 : slotOf[M & ~(1 << 5)];
            P.nd[d][n].sl = -1;
            ++n;
        }
        int pend[20] = {}; int np = 0;            // phase 1b: childful into free slots
        for (int M = 1; M < 64; ++M) {
            if (pc6(M) != d || msb6(M) >= 5) continue;
            const int hi = msb6(M);
            int fs = -1;
            for (int s = 0; s < NSLOT; ++s) if (!busy[s]) { fs = s; break; }
            if (fs >= 0) {
                busy[fs] = true; slotOf[M] = fs;
                P.nd[d][n].jo = hi;
                P.nd[d][n].ps = (d == 1) ? -1 : slotOf[M & ~(1 << hi)];
                P.nd[d][n].sl = fs;
                ++n;
            } else pend[np++] = M;
        }
        P.n1[d] = n;
        int freeds[20] = {}; int nf = 0;          // phase 2: reuse msb==4 parents' slots
        if (d >= 2)
            for (int M = 1; M < 64; ++M)
                if (pc6(M) == d - 1 && msb6(M) == 4) freeds[nf++] = slotOf[M];
        for (int i = 0; i < np; ++i) {
            const int M = pend[i]; const int hi = msb6(M);
            const int s = freeds[--nf];
            slotOf[M] = s;
            P.nd[d][n].jo = hi;
            P.nd[d][n].ps = slotOf[M & ~(1 << hi)];
            P.nd[d][n].sl = s;
            ++n;
        }
        P.cnt[d] = n;
        for (int s = 0; s < NSLOT; ++s) busy[s] = false;
        for (int M = 1; M < 64; ++M)
            if (pc6(M) == d && msb6(M) < 5) busy[slotOf[M]] = true;
    }
    return P;
}
constexpr Plan PL = make_plan();

// Runtime node table (kernarg): rec = jo | (ps+1)<<3 | (sl+1)<<8
struct KTab { unsigned rec[63]; int cnt[8]; int n1[8]; };

#define LOG2E   1.44269504f
#define TWOL2E  2.88539008f
#define SLOT_SH 2048            // shorts per slot (4 KB), both h and c pools

__device__ __forceinline__ unsigned short f2bf(float x) {
    union { float f; unsigned int u; } a; a.f = x;
    unsigned int r = (a.u + 0x7FFFu + ((a.u >> 16) & 1u)) >> 16;
    return (unsigned short)r;
}
__device__ __forceinline__ unsigned pk2(float a, float b) {
    union { __hip_bfloat162 h; unsigned u; } z;
    z.h = __float22bfloat162_rn(float2{a, b});
    return z.u;
}
__device__ __forceinline__ float bflo(unsigned p) {
    union { unsigned u; float f; } a; a.u = p << 16; return a.f;
}
__device__ __forceinline__ float bfhi(unsigned p) {
    union { unsigned u; float f; } a; a.u = p & 0xFFFF0000u; return a.f;
}

// h pool:  hs[((slot*16 + kslot)*NSAMP + n)*8 + j]  = h[ch = kslot*8+j][sample n]
//   B-frag chunk q, lane (quad,m16): kslot = q*4+quad -> b128 at slot*4KB + q*1KB + lane part
//   wave w writes ch = w*16+quad*4+r at kslot = w*2+(quad>>1), j = (quad&1)*4+r
// c pool:  csb[((slot*32 + cgrp)*NSAMP + n)*4 + r]  = c[ch = cgrp*4+r][sample n], bf16
//   lane (w,quad,m16): cgrp = w*4+quad, b64 read/write, conflict-free (8B x 16 lanes)

__global__ __launch_bounds__(BLOCK)
void subset_lstm_rolled_kernel(
    const float* __restrict__ x_input,
    const float* __restrict__ W_ih,
    const float* __restrict__ W_hh,
    const float* __restrict__ b_ih,
    const float* __restrict__ b_hh,
    const float* __restrict__ fc1_W,
    const float* __restrict__ fc1_b,
    const float* __restrict__ fc2_W,
    const float* __restrict__ fc2_b,
    float* __restrict__ out,
    KTab tab)
{
    __shared__ __align__(16) unsigned short hs [NSLOT * SLOT_SH];       // 64 KB
    __shared__ __align__(16) unsigned short csb[NSLOT * SLOT_SH];       // 64 KB
    __shared__ __align__(16) unsigned short xb[NOBJ * 4 * NSAMP * 8];   // 6 KB
    float* s_maxh  = (float*)hs;                 // 8 KB  (post-LSTM alias)
    float* s_fc1   = (float*)(hs + 4096);        // 16 KB (post-LSTM alias)
    float* s_logit = (float*)xb;

    const int t      = threadIdx.x;
    const int w      = t >> 6;
    const int lane   = t & 63;
    const int quad   = lane >> 4;
    const int m16    = lane & 15;
    const int s_base = blockIdx.x * NSAMP;

    // ---- x B-chunks: xb[obj][quad'][n][j]; quad2 carries 1.0 at j0 (bias), quad3 zero ----
    for (int idx = t; idx < NOBJ * 4 * NSAMP * 8; idx += BLOCK) {
        const int j = idx & 7, n = (idx >> 3) & 15, q = (idx >> 7) & 3, obj = idx >> 9;
        float v;
        if (q < 2) v = x_input[(s_base + n) * (NOBJ * DDIM) + obj * DDIM + q * 8 + j];
        else       v = (q == 2 && j == 0) ? 1.0f : 0.0f;
        xb[idx] = f2bf(v);
    }

    // ---- persistent A-frags wf[gate][chunk], PRE-SCALED (verified R8/R9) ----
    // gates i,f,o: row *= -log2e ; gate g: row *= 2*log2e. Bias at (quad2,j0) vs B's 1.0.
    bf16x8 wf[4][5];
    #pragma unroll
    for (int g = 0; g < 4; ++g) {
        const float sc = (g == 2) ? TWOL2E : -LOG2E;
        const int grow = g * HDIM + w * 16 + m16;
        const float* whr = W_hh + grow * HDIM;
        const float* wir = W_ih + grow * DDIM;
        #pragma unroll
        for (int q = 0; q < 4; ++q) {
            union { unsigned short u[8]; bf16x8 v; } pk;
            #pragma unroll
            for (int j = 0; j < 8; ++j)
                pk.u[j] = f2bf(sc * whr[q * 32 + quad * 8 + j]);
            wf[g][q] = pk.v;
        }
        {
            union { unsigned short u[8]; bf16x8 v; } pk;
            #pragma unroll
            for (int j = 0; j < 8; ++j) {
                float v = 0.0f;
                if (quad < 2) v = sc * wir[quad * 8 + j];
                else if (quad == 2 && j == 0) v = sc * (b_ih[grow] + b_hh[grow]);
                pk.u[j] = f2bf(v);
            }
            wf[g][4] = pk.v;
        }
    }

    // per-lane LDS address parts (shorts -> byte via *2 done by compiler folding)
    unsigned short* const h_rd_lane = &hs [(quad * NSAMP + m16) * 8];              // + slot*4KB(s) + q*1KB(imm)
    unsigned short* const h_wr_lane = &hs [(((w * 2 + (quad >> 1)) * NSAMP) + m16) * 8 + (quad & 1) * 4];
    unsigned short* const c_lane    = &csb[(((w * 4 + quad) * NSAMP) + m16) * 4];  // + slot*4KB(s)
    const f32x4 fzero = {0.f, 0.f, 0.f, 0.f};

    float mh[4] = {-1e30f, -1e30f, -1e30f, -1e30f};
    int base = 0;

    #pragma clang loop unroll(disable)
    for (int d = 1; d <= 6; ++d) {
        __syncthreads();
        const int cnt = tab.cnt[d];
        const int n1  = tab.n1[d];
        #pragma clang loop unroll(disable)
        for (int ni = 0; ni < cnt; ++ni) {
            if (ni == n1) __syncthreads();   // slot-recycle barrier (uniform; L3 only)
            const unsigned rec = tab.rec[base + ni];
            const int jo = (int)(rec & 7u);
            const int ps = (int)((rec >> 3) & 31u) - 1;
            const int sl = (int)((rec >> 8) & 31u) - 1;

            // early cprev read (latency hidden behind MFMAs)
            float cp[4] = {0.f, 0.f, 0.f, 0.f};
            if (ps >= 0) {
                const uint2 cpk = *(const uint2*)(c_lane + ps * SLOT_SH);
                cp[0] = bflo(cpk.x); cp[1] = bfhi(cpk.x);
                cp[2] = bflo(cpk.y); cp[3] = bfhi(cpk.y);
            }

            f32x4 acc[4];
            {   // x + bias chunk (C=0 operand: no acc-init instructions)
                const bf16x8 bfx = *(const bf16x8*)&xb[((jo * 4 + quad) * NSAMP + m16) * 8];
                #pragma unroll
                for (int g = 0; g < 4; ++g)
                    acc[g] = __builtin_amdgcn_mfma_f32_16x16x32_bf16(
                        wf[g][4], bfx, fzero, 0, 0, 0);
            }
            if (ps >= 0) {
                const unsigned short* hb = h_rd_lane + ps * SLOT_SH;
                #pragma unroll
                for (int q = 0; q < 4; ++q) {
                    const bf16x8 bh = *(const bf16x8*)(hb + q * (SLOT_SH / 4));
                    #pragma unroll
                    for (int g = 0; g < 4; ++g)
                        acc[g] = __builtin_amdgcn_mfma_f32_16x16x32_bf16(
                            wf[g][q], bh, acc[g], 0, 0, 0);
                }
            }

            // fused pointwise (verified R9): ch c = w*16+quad*4+r, sample m16
            float cn4[4], hn4[4];
            #pragma unroll
            for (int r = 0; r < 4; ++r) {
                const float u  = 1.0f + __builtin_amdgcn_exp2f(acc[0][r]);
                const float q  = 1.0f + __builtin_amdgcn_exp2f(acc[1][r]);
                const float v  = 1.0f + __builtin_amdgcn_exp2f(acc[2][r]);
                const float qo = 1.0f + __builtin_amdgcn_exp2f(acc[3][r]);
                const float uv  = u * v;
                const float num = fmaf(q, v - 2.0f, cp[r] * uv);
                const float cn  = num * __builtin_amdgcn_rcpf(q * uv);
                const float wt  = 1.0f + __builtin_amdgcn_exp2f(TWOL2E * cn);
                const float h   = (wt - 2.0f) * __builtin_amdgcn_rcpf(qo * wt);
                cn4[r] = cn; hn4[r] = h;
                mh[r] = fmaxf(mh[r], h);
            }

            if (sl >= 0) {   // childful: publish h (B-layout) and c (bf16)
                uint2 cw; cw.x = pk2(cn4[0], cn4[1]); cw.y = pk2(cn4[2], cn4[3]);
                *(uint2*)(c_lane + sl * SLOT_SH) = cw;
                uint2 hw; hw.x = pk2(hn4[0], hn4[1]); hw.y = pk2(hn4[2], hn4[3]);
                *(uint2*)(h_wr_lane + sl * SLOT_SH) = hw;
            }
        }
        base += cnt;
    }

    __syncthreads();   // pools dead; reuse hs for epilogue
    {
        float4 v; v.x = mh[0]; v.y = mh[1]; v.z = mh[2]; v.w = mh[3];
        *(float4*)&s_maxh[m16 * HDIM + w * 16 + quad * 4] = v;
    }
    __syncthreads();

    // ---- FC1: f = t&255, sample half t>>8 (8 samples each) ----
    {
        const int f  = t & 255;
        const int sh = t >> 8;
        float a1[8];
        #pragma unroll
        for (int s = 0; s < 8; ++s) a1[s] = fc1_b[f];
        for (int k4 = 0; k4 < HDIM / 4; ++k4) {
            const float4 wv = *(const float4*)&fc1_W[f * HDIM + k4 * 4];
            #pragma unroll
            for (int s = 0; s < 8; ++s) {
                const float4 h4 = *(const float4*)&s_maxh[(sh * 8 + s) * HDIM + k4 * 4];
                a1[s] += wv.x * h4.x + wv.y * h4.y + wv.z * h4.z + wv.w * h4.w;
            }
        }
        #pragma unroll
        for (int s = 0; s < 8; ++s)
            s_fc1[(sh * 8 + s) * 256 + f] = fmaxf(a1[s], 0.0f);
    }
    __syncthreads();

    if (t < NSAMP * 10) {
        const int s = t / 10, a = t % 10;
        float acc2 = fc2_b[a];
        for (int f4 = 0; f4 < 256 / 4; ++f4) {
            const float4 wv = *(const float4*)&fc2_W[a * 256 + f4 * 4];
            const float4 v  = *(const float4*)&s_fc1[s * 256 + f4 * 4];
            acc2 += wv.x * v.x + wv.y * v.y + wv.z * v.z + wv.w * v.w;
        }
        s_logit[s * 10 + a] = acc2;
    }
    __syncthreads();

    if (t < NSAMP) {
        float m = -1e30f;
        #pragma unroll
        for (int a = 0; a < 10; ++a) m = fmaxf(m, s_logit[t * 10 + a]);
        float sum = 0.0f;
        #pragma unroll
        for (int a = 0; a < 10; ++a) sum += __expf(s_logit[t * 10 + a] - m);
        const float lse = m + __logf(sum);
        #pragma unroll
        for (int a = 0; a < 10; ++a)
            out[(s_base + t) * 10 + a] = s_logit[t * 10 + a] - lse;
    }
}

extern "C" void kernel_launch(void* const* d_in, const int* in_sizes, int n_in,
                              void* d_out, int out_size, void* d_ws, size_t ws_size,
                              hipStream_t stream)
{
    (void)d_ws; (void)ws_size; (void)n_in; (void)out_size;

    // flatten the verified constexpr plan into the runtime kernarg table
    KTab tab{};
    int k = 0;
    for (int d = 1; d <= 6; ++d) {
        tab.cnt[d] = PL.cnt[d];
        tab.n1[d]  = (PL.n1[d] == PL.cnt[d]) ? 0x7fffffff : PL.n1[d];  // no-barrier sentinel
        for (int i = 0; i < PL.cnt[d]; ++i)
            tab.rec[k++] = (unsigned)PL.nd[d][i].jo
                         | ((unsigned)(PL.nd[d][i].ps + 1) << 3)
                         | ((unsigned)(PL.nd[d][i].sl + 1) << 8);
    }

    const float* x   = (const float*)d_in[0];
    const float* Wih = (const float*)d_in[1];
    const float* Whh = (const float*)d_in[2];
    const float* bih = (const float*)d_in[3];
    const float* bhh = (const float*)d_in[4];
    const float* f1w = (const float*)d_in[5];
    const float* f1b = (const float*)d_in[6];
    const float* f2w = (const float*)d_in[7];
    const float* f2b = (const float*)d_in[8];

    const int mb = in_sizes[0] / (NOBJ * DDIM);   // 8192
    dim3 grid(mb / NSAMP), block(BLOCK);
    subset_lstm_rolled_kernel<<<grid, block, 0, stream>>>(
        x, Wih, Whh, bih, bhh, f1w, f1b, f2w, f2b, (float*)d_out, tab);
}

// Round 11
// 196.913 us; speedup vs baseline: 1.1320x; 1.1320x over previous
//
#include <hip/hip_runtime.h>
#include <hip/hip_bf16.h>

#define BLOCK   512     // 8 waves; wave w owns channels w*16..w*16+15, all 4 gates
#define NSAMP   16
#define HDIM    128
#define DDIM    16
#define NOBJ    6
#define NSLOT   14      // h/c slot pool: 56 KB -> total LDS < 64 KB (2 blocks/CU)

typedef __attribute__((ext_vector_type(8))) short bf16x8;
typedef __attribute__((ext_vector_type(4))) float f32x4;

constexpr int pc6(int m)  { int c = 0; for (int i = 0; i < 6; ++i) c += (m >> i) & 1; return c; }
constexpr int msb6(int m) { int b = -1; for (int i = 0; i < 6; ++i) if (m & (1 << i)) b = i; return b; }

// Compile-time BFS plan, NSLOT-slot allocator with multi-phase recycling.
// Node = subset mask M; appended obj jo = msb(M); childful iff jo < 5.
// Per level: leaves first (read-only), then childful placed in phases limited
// by free slots; between phases a barrier, after which parent slots whose
// children are all processed are recycled. bar flag = barrier before node.
struct PNode { int jo, ps, sl; bool bar; };
struct Plan2 { PNode nd[63]; int lvlStart[8]; };
constexpr Plan2 make_plan2() {
    Plan2 P{};
    int slotOf[64] = {};
    bool busy[NSLOT] = {};
    int k = 0;
    for (int d = 1; d <= 6; ++d) {
        P.lvlStart[d] = k;
        for (int M = 1; M < 64; ++M) {               // leaves (msb==5): no slot
            if (pc6(M) != d || msb6(M) != 5) continue;
            P.nd[k].jo = 5;
            P.nd[k].ps = (d == 1) ? -1 : slotOf[M & ~(1 << 5)];
            P.nd[k].sl = -1;
            P.nd[k].bar = false;
            ++k;
        }
        int pend[20] = {}; int np = 0;               // childful, pending placement
        for (int M = 1; M < 64; ++M)
            if (pc6(M) == d && msb6(M) < 5) pend[np++] = M;
        int key[20] = {};                            // parent's cf-children count
        for (int i = 0; i < np; ++i) {
            if (d == 1) { key[i] = 0; continue; }
            const int par = pend[i] & ~(1 << msb6(pend[i]));
            int c2 = 0;
            for (int j2 = 0; j2 < np; ++j2)
                if ((pend[j2] & ~(1 << msb6(pend[j2]))) == par) ++c2;
            key[i] = c2;
        }
        for (int a = 0; a < np; ++a)                 // sort by key asc (frees parents sooner)
            for (int b2 = a + 1; b2 < np; ++b2)
                if (key[b2] < key[a]) {
                    int tm = key[a]; key[a] = key[b2]; key[b2] = tm;
                    tm = pend[a]; pend[a] = pend[b2]; pend[b2] = tm;
                }
        bool placed[20] = {};
        int nplaced = 0;
        bool firstPhase = true;
        while (nplaced < np) {
            bool needBar = !firstPhase;
            bool any = false;
            for (int i = 0; i < np; ++i) {
                if (placed[i]) continue;
                int fs = -1;
                for (int s = 0; s < NSLOT; ++s) if (!busy[s]) { fs = s; break; }
                if (fs < 0) break;
                const int M = pend[i]; const int hi = msb6(M);
                busy[fs] = true; slotOf[M] = fs;
                P.nd[k].jo = hi;
                P.nd[k].ps = (d == 1) ? -1 : slotOf[M & ~(1 << hi)];
                P.nd[k].sl = fs;
                P.nd[k].bar = needBar; needBar = false;
                ++k; placed[i] = true; ++nplaced; any = true;
            }
            firstPhase = false;
            if (nplaced < np) {
                if (!any) break;                     // would deadlock (never for NSLOT>=14)
                for (int M = 1; M < 64; ++M) {       // recycle finished parents
                    if (pc6(M) != d - 1 || msb6(M) >= 5) continue;
                    bool allp = true;
                    for (int i = 0; i < np; ++i)
                        if (!placed[i] &&
                            ((pend[i] & ~(1 << msb6(pend[i]))) == M)) allp = false;
                    if (allp) busy[slotOf[M]] = false;
                }
            }
        }
        for (int s = 0; s < NSLOT; ++s) busy[s] = false;   // live = this level's cf slots
        for (int M = 1; M < 64; ++M)
            if (pc6(M) == d && msb6(M) < 5) busy[slotOf[M]] = true;
    }
    P.lvlStart[7] = k;
    return P;
}
constexpr Plan2 PL2 = make_plan2();
static_assert(PL2.lvlStart[7] == 63, "plan must cover all 63 nodes");

#define LOG2E   1.44269504f
#define TWOL2E  2.88539008f
#define SLOT_SH 2048            // shorts per slot (4 KB)

__device__ __forceinline__ unsigned short f2bf(float x) {
    union { float f; unsigned int u; } a; a.f = x;
    unsigned int r = (a.u + 0x7FFFu + ((a.u >> 16) & 1u)) >> 16;
    return (unsigned short)r;
}
__device__ __forceinline__ unsigned pk2(float a, float b) {
    union { __hip_bfloat162 h; unsigned u; } z;
    z.h = __float22bfloat162_rn(float2{a, b});
    return z.u;
}
__device__ __forceinline__ float bflo(unsigned p) {
    union { unsigned u; float f; } a; a.u = p << 16; return a.f;
}
__device__ __forceinline__ float bfhi(unsigned p) {
    union { unsigned u; float f; } a; a.u = p & 0xFFFF0000u; return a.f;
}

// LDS h layout: hs[((slot*16 + kslot)*NSAMP + n)*8 + j] = h[ch = kslot*8+j][sample n]
// B-frag chunk q, lane (quad,m16): kslot = q*4+quad -> 16B-aligned ds_read_b128.
// Wave w writes ch = w*16+quad*4+r at kslot = w*2+(quad>>1), j = (quad&1)*4+r.

__global__ __launch_bounds__(BLOCK)
__attribute__((amdgpu_waves_per_eu(2, 4)))   // min 2 (VGPR cap 256, no spill); max 4 (2 blocks/CU)
void subset_lstm_l14_kernel(
    const float* __restrict__ x_input,
    const float* __restrict__ W_ih,
    const float* __restrict__ W_hh,
    const float* __restrict__ b_ih,
    const float* __restrict__ b_hh,
    const float* __restrict__ fc1_W,
    const float* __restrict__ fc1_b,
    const float* __restrict__ fc2_W,
    const float* __restrict__ fc2_b,
    float* __restrict__ out)
{
    __shared__ __align__(16) unsigned short hs[NSLOT * SLOT_SH];        // 56 KB
    __shared__ __align__(16) unsigned short xb[NOBJ * 2 * NSAMP * 8];   // 3 KB
    __shared__ __align__(16) unsigned short xpad[16];
    float* s_maxh  = (float*)hs;                 // 8 KB  (post-LSTM alias)
    float* s_fc1   = (float*)(hs + 4096);        // 16 KB (post-LSTM alias)
    float* s_logit = (float*)xb;

    const int t      = threadIdx.x;
    const int w      = t >> 6;
    const int lane   = t & 63;
    const int quad   = lane >> 4;
    const int m16    = lane & 15;
    const int s_base = blockIdx.x * NSAMP;

    if (t < 16) xpad[t] = (t == 0) ? f2bf(1.0f) : (unsigned short)0;

    // ---- x B-chunks (quads 0,1; quads 2,3 from xpad) ----
    for (int idx = t; idx < NOBJ * 2 * NSAMP * 8; idx += BLOCK) {
        const int j = idx & 7, n = (idx >> 3) & 15, q = (idx >> 7) & 1, obj = idx >> 8;
        xb[idx] = f2bf(x_input[(s_base + n) * (NOBJ * DDIM) + obj * DDIM + q * 8 + j]);
    }

    // ---- persistent A-frags wf[gate][chunk], PRE-SCALED (verified R8-R10) ----
    // gates i,f,o: row *= -log2e ; gate g: row *= 2*log2e. Bias at (quad2,j0) vs B's 1.0.
    bf16x8 wf[4][5];
    #pragma unroll
    for (int g = 0; g < 4; ++g) {
        const float sc = (g == 2) ? TWOL2E : -LOG2E;
        const int grow = g * HDIM + w * 16 + m16;
        const float* whr = W_hh + grow * HDIM;
        const float* wir = W_ih + grow * DDIM;
        #pragma unroll
        for (int q = 0; q < 4; ++q) {
            union { unsigned short u[8]; bf16x8 v; } pk;
            #pragma unroll
            for (int j = 0; j < 8; ++j)
                pk.u[j] = f2bf(sc * whr[q * 32 + quad * 8 + j]);
            wf[g][q] = pk.v;
        }
        {
            union { unsigned short u[8]; bf16x8 v; } pk;
            #pragma unroll
            for (int j = 0; j < 8; ++j) {
                float v = 0.0f;
                if (quad < 2) v = sc * wir[quad * 8 + j];
                else if (quad == 2 && j == 0) v = sc * (b_ih[grow] + b_hh[grow]);
                pk.u[j] = f2bf(v);
            }
            wf[g][4] = pk.v;
        }
    }

    uint2 cs[NSLOT];   // c-state: 4 bf16 per lane, static slot indices
    float mh[4] = {-1e30f, -1e30f, -1e30f, -1e30f};
    const int kslot = w * 2 + (quad >> 1);

    #pragma unroll
    for (int d = 1; d <= 6; ++d) {
        __syncthreads();
        #pragma unroll
        for (int k = PL2.lvlStart[d]; k < PL2.lvlStart[d + 1]; ++k) {
            if (PL2.nd[k].bar) __syncthreads();   // intra-level recycle barrier (constexpr)
            const int jo = PL2.nd[k].jo;
            const int ps = PL2.nd[k].ps;
            const int sl = PL2.nd[k].sl;

            f32x4 acc[4];
            #pragma unroll
            for (int g = 0; g < 4; ++g)
                acc[g] = f32x4{0.f, 0.f, 0.f, 0.f};

            {   // x + bias chunk
                const unsigned short* bp = (quad < 2)
                    ? &xb[((jo * 2 + quad) * NSAMP + m16) * 8]
                    : &xpad[(quad - 2) * 8];
                const bf16x8 bfx = *(const bf16x8*)bp;
                #pragma unroll
                for (int g = 0; g < 4; ++g)
                    acc[g] = __builtin_amdgcn_mfma_f32_16x16x32_bf16(
                        wf[g][4], bfx, acc[g], 0, 0, 0);
            }
            if (ps >= 0) {
                #pragma unroll
                for (int q = 0; q < 4; ++q) {
                    const bf16x8 bh = *(const bf16x8*)
                        &hs[((ps * 16 + q * 4 + quad) * NSAMP + m16) * 8];
                    #pragma unroll
                    for (int g = 0; g < 4; ++g)
                        acc[g] = __builtin_amdgcn_mfma_f32_16x16x32_bf16(
                            wf[g][q], bh, acc[g], 0, 0, 0);
                }
            }

            // fused pointwise (verified R9/R10): ch = w*16+quad*4+r, sample m16
            float cn4[4], hn4[4];
            #pragma unroll
            for (int r = 0; r < 4; ++r) {
                float cprev = 0.0f;
                if (ps >= 0) {
                    const unsigned p = (r < 2) ? cs[ps].x : cs[ps].y;
                    cprev = (r & 1) ? bfhi(p) : bflo(p);
                }
                const float u  = 1.0f + __builtin_amdgcn_exp2f(acc[0][r]);
                const float q  = 1.0f + __builtin_amdgcn_exp2f(acc[1][r]);
                const float v  = 1.0f + __builtin_amdgcn_exp2f(acc[2][r]);
                const float qo = 1.0f + __builtin_amdgcn_exp2f(acc[3][r]);
                const float uv  = u * v;
                const float num = fmaf(q, v - 2.0f, cprev * uv);
                const float cn  = num * __builtin_amdgcn_rcpf(q * uv);
                const float wt  = 1.0f + __builtin_amdgcn_exp2f(TWOL2E * cn);
                const float h   = (wt - 2.0f) * __builtin_amdgcn_rcpf(qo * wt);
                cn4[r] = cn; hn4[r] = h;
                mh[r] = fmaxf(mh[r], h);
            }

            if (sl >= 0) {   // childful: publish c (regs) and h (B-layout LDS)
                cs[sl].x = pk2(cn4[0], cn4[1]);
                cs[sl].y = pk2(cn4[2], cn4[3]);
                union { __hip_bfloat162 h2[2]; uint2 v; } hp;
                hp.h2[0] = __float22bfloat162_rn(float2{hn4[0], hn4[1]});
                hp.h2[1] = __float22bfloat162_rn(float2{hn4[2], hn4[3]});
                *(uint2*)&hs[((sl * 16 + kslot) * NSAMP + m16) * 8
                             + (quad & 1) * 4] = hp.v;
            }
        }
    }

    __syncthreads();   // h slots dead; reuse hs for epilogue
    {
        float4 v; v.x = mh[0]; v.y = mh[1]; v.z = mh[2]; v.w = mh[3];
        *(float4*)&s_maxh[m16 * HDIM + w * 16 + quad * 4] = v;
    }
    __syncthreads();

    // ---- FC1: f = t&255, sample half t>>8 (8 samples each) ----
    {
        const int f  = t & 255;
        const int sh = t >> 8;
        float a1[8];
        #pragma unroll
        for (int s = 0; s < 8; ++s) a1[s] = fc1_b[f];
        for (int k4 = 0; k4 < HDIM / 4; ++k4) {
            const float4 wv = *(const float4*)&fc1_W[f * HDIM + k4 * 4];
            #pragma unroll
            for (int s = 0; s < 8; ++s) {
                const float4 h4 = *(const float4*)&s_maxh[(sh * 8 + s) * HDIM + k4 * 4];
                a1[s] += wv.x * h4.x + wv.y * h4.y + wv.z * h4.z + wv.w * h4.w;
            }
        }
        #pragma unroll
        for (int s = 0; s < 8; ++s)
            s_fc1[(sh * 8 + s) * 256 + f] = fmaxf(a1[s], 0.0f);
    }
    __syncthreads();

    if (t < NSAMP * 10) {
        const int s = t / 10, a = t % 10;
        float acc2 = fc2_b[a];
        for (int f4 = 0; f4 < 256 / 4; ++f4) {
            const float4 wv = *(const float4*)&fc2_W[a * 256 + f4 * 4];
            const float4 v  = *(const float4*)&s_fc1[s * 256 + f4 * 4];
            acc2 += wv.x * v.x + wv.y * v.y + wv.z * v.z + wv.w * v.w;
        }
        s_logit[s * 10 + a] = acc2;
    }
    __syncthreads();

    if (t < NSAMP) {
        float m = -1e30f;
        #pragma unroll
        for (int a = 0; a < 10; ++a) m = fmaxf(m, s_logit[t * 10 + a]);
        float sum = 0.0f;
        #pragma unroll
        for (int a = 0; a < 10; ++a) sum += __expf(s_logit[t * 10 + a] - m);
        const float lse = m + __logf(sum);
        #pragma unroll
        for (int a = 0; a < 10; ++a)
            out[(s_base + t) * 10 + a] = s_logit[t * 10 + a] - lse;
    }
}

extern "C" void kernel_launch(void* const* d_in, const int* in_sizes, int n_in,
                              void* d_out, int out_size, void* d_ws, size_t ws_size,
                              hipStream_t stream)
{
    (void)d_ws; (void)ws_size; (void)n_in; (void)out_size;

    const float* x   = (const float*)d_in[0];
    const float* Wih = (const float*)d_in[1];
    const float* Whh = (const float*)d_in[2];
    const float* bih = (const float*)d_in[3];
    const float* bhh = (const float*)d_in[4];
    const float* f1w = (const float*)d_in[5];
    const float* f1b = (const float*)d_in[6];
    const float* f2w = (const float*)d_in[7];
    const float* f2b = (const float*)d_in[8];

    const int mb = in_sizes[0] / (NOBJ * DDIM);   // 8192
    dim3 grid(mb / NSAMP), block(BLOCK);
    subset_lstm_l14_kernel<<<grid, block, 0, stream>>>(
        x, Wih, Whh, bih, bhh, f1w, f1b, f2w, f2b, (float*)d_out);
}